// Round 2
// baseline (166.729 us; speedup 1.0000x reference)
//
#include <hip/hip_runtime.h>
#include <hip/hip_bf16.h>

#define NROWS  8192
#define DIM    256
#define NCLASS 512
#define MARGIN 0.3f

using bf16x8 = __attribute__((ext_vector_type(8))) short;
using f32x4  = __attribute__((ext_vector_type(4))) float;

__device__ inline ushort f2bf(float f) {
    __hip_bfloat16 h = __float2bfloat16(f);
    return *reinterpret_cast<ushort*>(&h);
}
__device__ inline float bf2f(ushort u) {
    return __uint_as_float(((unsigned)u) << 16);
}
// Order-preserving float<->uint transform: bitwise atomicMax/Min == float max/min.
__device__ inline unsigned f2ord(float f) {
    unsigned b = __float_as_uint(f);
    return (b & 0x80000000u) ? ~b : (b | 0x80000000u);
}
__device__ inline float ord2f(unsigned u) {
    return __uint_as_float((u & 0x80000000u) ? (u & 0x7FFFFFFFu) : ~u);
}

// ---- workspace layout (bytes) ----
#define XBS_OFF 0u            // 8192*256*2 = 4194304  sorted bf16 rows
#define SQS_OFF 4194304u      // 32768  sorted ||x||^2
#define TGT_OFF 4227072u      // 32768  sorted targets (int)
#define PMX_OFF 4259840u      // 32768  ordered-uint max over positives of (sqc-2acc)
#define NMN_OFF 4292608u      // 32768  ordered-uint min over negatives
#define BIN_OFF 4325376u      // 2048   class bin cursors
#define ACC_OFF 4327424u      // 8      double loss accumulator
#define TIK_OFF 4327432u      // 4      completion ticket

// K1: one block. Histogram of targets -> exclusive scan -> bin cursors.
__global__ __launch_bounds__(512) void hist_scan_kernel(
    const int* __restrict__ tgt, int* __restrict__ bincur,
    double* __restrict__ accd, unsigned* __restrict__ ticket)
{
    __shared__ int h[NCLASS];
    int tid = threadIdx.x;
    h[tid] = 0;
    if (tid == 0) { *accd = 0.0; *ticket = 0u; }
    __syncthreads();
    for (int k = 0; k < NROWS / NCLASS; ++k)
        atomicAdd(&h[tgt[tid + k * NCLASS]], 1);
    __syncthreads();
    int cnt = h[tid];
    for (int ofs = 1; ofs < NCLASS; ofs <<= 1) {
        int v = (tid >= ofs) ? h[tid - ofs] : 0;
        __syncthreads();
        h[tid] += v;
        __syncthreads();
    }
    bincur[tid] = h[tid] - cnt;
}

// K2: one wave per row. Normalize fp32 -> bf16, scatter to class-sorted slot.
__global__ __launch_bounds__(256) void norm_scatter_kernel(
    const float* __restrict__ in, const int* __restrict__ tgt,
    int* __restrict__ bincur, ushort* __restrict__ xbs,
    float* __restrict__ sqs, int* __restrict__ tgts,
    unsigned* __restrict__ pmax, unsigned* __restrict__ nmin)
{
    int row  = blockIdx.x * 4 + (threadIdx.x >> 6);
    int lane = threadIdx.x & 63;
    float4 v = ((const float4*)(in + (size_t)row * DIM))[lane];
    float ss = v.x * v.x + v.y * v.y + v.z * v.z + v.w * v.w;
#pragma unroll
    for (int m = 1; m < 64; m <<= 1) ss += __shfl_xor(ss, m, 64);
    float inv = 1.0f / (sqrtf(ss) + 1e-12f);

    ushort4 st;
    st.x = f2bf(v.x * inv); st.y = f2bf(v.y * inv);
    st.z = f2bf(v.z * inv); st.w = f2bf(v.w * inv);

    int t = 0, dst = 0;
    if (lane == 0) { t = tgt[row]; dst = atomicAdd(&bincur[t], 1); }
    dst = __shfl(dst, 0); t = __shfl(t, 0);

    ((ushort4*)(xbs + (size_t)dst * DIM))[lane] = st;

    float a0 = bf2f(st.x), a1 = bf2f(st.y), a2 = bf2f(st.z), a3 = bf2f(st.w);
    float s2 = a0 * a0 + a1 * a1 + a2 * a2 + a3 * a3;
#pragma unroll
    for (int m = 1; m < 64; m <<= 1) s2 += __shfl_xor(s2, m, 64);
    if (lane == 0) {
        sqs[dst]  = s2;
        tgts[dst] = t;
        pmax[dst] = 0x007FFFFFu;  // f2ord(-inf)
        nmin[dst] = 0xFF800000u;  // f2ord(+inf)
    }
}

// K3: fused gram + hard-pos/hard-neg, NO LDS staging of B.
// The whole bf16 matrix (4.2 MB) is L2-resident; per-block B panel is 256 KB.
// LDS staging was pure overhead: 16 barriers serialized MFMA/LDS/VALU pipes
// (measured 29% MFMA + 22% LDS + 27% VALU ~= sum, not max). Each wave streams
// its B fragments straight from L2 with register double-buffering (bfA/bfB,
// static names per the runtime-index-scratch rule) and no per-stage barriers,
// so free-running waves overlap loads, MFMA, and epilogue VALU.
// Per b128 load: 16 rows x 64 contiguous bytes -> every fetched line consumed.
// XCD supertile swizzle: grid 512 = 8 supertiles of 8x8 blocks; each XCD
// (id%8, round-robin dispatch) gets one supertile -> L2 working set
// 2048 rows (1MB) + 4096 cols (2MB) = 3 MB < 4 MB per-XCD L2.
__global__ __launch_bounds__(256, 2) void gram_kernel(
    const ushort* __restrict__ xbs, const float* __restrict__ sqs,
    const int* __restrict__ tgts, unsigned* __restrict__ pmax,
    unsigned* __restrict__ nmin)
{
    __shared__ struct {
        float sqc[512];        // per-col ||x||^2 for this 512-col chunk
        int   tgc[512];        // per-col class
        int   tga[256];        // per-row class for this block's 256 rows
    } sm;

    const int wave = threadIdx.x >> 6;
    const int lane = threadIdx.x & 63;
    const int l15  = lane & 15;
    const int quad = lane >> 4;

    // XCD supertile swizzle (bijective): product of bijections
    // (xcd&3, w&7) -> bx in [0,32), (xcd>>2, w>>3) -> by in [0,16).
    const int id  = blockIdx.x;
    const int xcd = id & 7;
    const int w   = id >> 3;
    const int bx  = (xcd & 3) * 8 + (w & 7);   // 0..31  (256 rows each)
    const int by  = (xcd >> 2) * 8 + (w >> 3); // 0..15  (512 cols each)

    const int mbase = bx * 256 + wave * 64;
    const int nbase = by * 512;

    // Stage per-chunk metadata into LDS (once; the only barrier in the kernel).
    {
        int c = threadIdx.x * 2;
        sm.sqc[c]     = sqs[nbase + c];
        sm.sqc[c + 1] = sqs[nbase + c + 1];
        sm.tgc[c]     = tgts[nbase + c];
        sm.tgc[c + 1] = tgts[nbase + c + 1];
        sm.tga[threadIdx.x] = tgts[bx * 256 + threadIdx.x];
    }

    // Preload A fragments: 4 tiles x full K=256 (resident for the whole kernel).
    bf16x8 afrag[4][8];
#pragma unroll
    for (int a = 0; a < 4; ++a) {
        const ushort* arow = xbs + (size_t)(mbase + a * 16 + l15) * DIM + quad * 8;
#pragma unroll
        for (int kk = 0; kk < 8; ++kk)
            afrag[a][kk] = *(const bf16x8*)(arow + kk * 32);
    }
    const int rlo = tgts[mbase];       // sorted => wave row-class range
    const int rhi = tgts[mbase + 63];

    __syncthreads();  // metadata visible

    float pm[16], nm[16];
#pragma unroll
    for (int j = 0; j < 16; ++j) { pm[j] = -__builtin_inff(); nm[j] = __builtin_inff(); }

    // B fragment base: lane reads row (nbase + t*16 + l15), k = quad*8 + kk*32.
    const ushort* bbase = xbs + (size_t)nbase * DIM + quad * 8;

    bf16x8 bfA[8], bfB[8];

    // Load half of a B tile (4 of 8 k-fragments) — smaller live ranges than a
    // full-tile load, keeps peak VGPR pressure under the 256 cap at 2 blk/CU.
#define LOADB_H(buf, t, h) do {                                              \
        const ushort* p_ = bbase + (size_t)((t) * 16 + l15) * DIM;           \
        _Pragma("unroll")                                                    \
        for (int kk = 4 * (h); kk < 4 * (h) + 4; ++kk)                       \
            buf[kk] = *(const bf16x8*)(p_ + kk * 32);                        \
    } while (0)

    // One 16-col tile: 2 half-steps; each half = 16 MFMA over 2 a-chains,
    // epilogue applied per-half so only 2 f32x4 accumulators are ever live.
#define TILE(t, buf, pt, pbuf) do {                                          \
        const int   t16_ = (t) * 16;                                         \
        const float sqc_ = sm.sqc[t16_ + l15];                               \
        const int   clo_ = sm.tgc[t16_], chi_ = sm.tgc[t16_ + 15];           \
        const int   tc_  = sm.tgc[t16_ + l15];                               \
        const bool  slow_ = (rlo <= chi_ && clo_ <= rhi);                    \
        _Pragma("unroll")                                                    \
        for (int h = 0; h < 2; ++h) {                                        \
            f32x4 acc0_ = {0.f, 0.f, 0.f, 0.f};                              \
            f32x4 acc1_ = {0.f, 0.f, 0.f, 0.f};                              \
            if ((pt) >= 0) LOADB_H(pbuf, pt, h);  /* prefetch next tile */   \
            __builtin_amdgcn_s_setprio(1);                                   \
            _Pragma("unroll")                                                \
            for (int kk = 0; kk < 8; ++kk) {                                 \
                acc0_ = __builtin_amdgcn_mfma_f32_16x16x32_bf16(             \
                            afrag[2 * h][kk],     buf[kk], acc0_, 0, 0, 0);  \
                acc1_ = __builtin_amdgcn_mfma_f32_16x16x32_bf16(             \
                            afrag[2 * h + 1][kk], buf[kk], acc1_, 0, 0, 0);  \
            }                                                                \
            __builtin_amdgcn_s_setprio(0);                                   \
            if (slow_) {                                                     \
                _Pragma("unroll")                                            \
                for (int i = 0; i < 4; ++i) {                                \
                    const float v0_ = fmaf(acc0_[i], -2.0f, sqc_);           \
                    const bool  s0_ = (sm.tga[wave * 64 + (2 * h) * 16 + quad * 4 + i] == tc_); \
                    pm[(2 * h) * 4 + i] = fmaxf(pm[(2 * h) * 4 + i], s0_ ? v0_ : -__builtin_inff()); \
                    nm[(2 * h) * 4 + i] = fminf(nm[(2 * h) * 4 + i], s0_ ? __builtin_inff() : v0_);  \
                    const float v1_ = fmaf(acc1_[i], -2.0f, sqc_);           \
                    const bool  s1_ = (sm.tga[wave * 64 + (2 * h + 1) * 16 + quad * 4 + i] == tc_); \
                    pm[(2 * h + 1) * 4 + i] = fmaxf(pm[(2 * h + 1) * 4 + i], s1_ ? v1_ : -__builtin_inff()); \
                    nm[(2 * h + 1) * 4 + i] = fminf(nm[(2 * h + 1) * 4 + i], s1_ ? __builtin_inff() : v1_);  \
                }                                                            \
            } else {                                                         \
                _Pragma("unroll")                                            \
                for (int i = 0; i < 4; ++i) {                                \
                    nm[(2 * h) * 4 + i]     = fminf(nm[(2 * h) * 4 + i],     fmaf(acc0_[i], -2.0f, sqc_)); \
                    nm[(2 * h + 1) * 4 + i] = fminf(nm[(2 * h + 1) * 4 + i], fmaf(acc1_[i], -2.0f, sqc_)); \
                }                                                            \
            }                                                                \
        }                                                                    \
    } while (0)

    // Main loop over 32 col-tiles, register double-buffered; the prefetch of
    // tile t+1 is issued inside TILE(t) (half at a time, ahead of each MFMA
    // cluster) so load-to-use distance is ~16 MFMA + epilogue VALU.
    LOADB_H(bfA, 0, 0);
    LOADB_H(bfA, 0, 1);
#pragma unroll 1
    for (int t = 0; t < 32; t += 2) {
        TILE(t, bfA, t + 1, bfB);
        TILE(t + 1, bfB, (t + 2 < 32) ? (t + 2) : -1, bfA);
    }
#undef LOADB_H
#undef TILE

    // Reduce across the 16 column-lanes (same quad), then one atomic per row.
#pragma unroll
    for (int m = 1; m < 16; m <<= 1) {
#pragma unroll
        for (int j = 0; j < 16; ++j) {
            pm[j] = fmaxf(pm[j], __shfl_xor(pm[j], m, 64));
            nm[j] = fminf(nm[j], __shfl_xor(nm[j], m, 64));
        }
    }
    if (l15 == 0) {
#pragma unroll
        for (int a = 0; a < 4; ++a)
#pragma unroll
            for (int i = 0; i < 4; ++i) {
                int r = mbase + a * 16 + quad * 4 + i;
                atomicMax(&pmax[r], f2ord(pm[a * 4 + i]));
                atomicMin(&nmin[r], f2ord(nm[a * 4 + i]));
            }
    }
}

// K4: multi-block finalize with fp64 atomic accumulation + completion ticket.
__global__ __launch_bounds__(256) void finalize_kernel(
    const unsigned* __restrict__ pmax, const unsigned* __restrict__ nmin,
    const float* __restrict__ sqs, double* __restrict__ accd,
    unsigned* __restrict__ ticket, float* __restrict__ out)
{
    int r = blockIdx.x * 256 + threadIdx.x;
    float pe = ord2f(pmax[r]);
    float ne = ord2f(nmin[r]);
    float ap = sqrtf(fmaxf(sqs[r] + pe, 0.0f));
    float an = (ne > 1e30f) ? (MARGIN + 1.0f) : sqrtf(fmaxf(sqs[r] + ne, 0.0f));
    float h  = fmaxf(ap - an + MARGIN, 0.0f);
    double s = (double)h;
#pragma unroll
    for (int m = 1; m < 64; m <<= 1) s += __shfl_xor(s, m, 64);
    __shared__ double sh[4];
    if ((threadIdx.x & 63) == 0) sh[threadIdx.x >> 6] = s;
    __syncthreads();
    if (threadIdx.x == 0) {
        double b = sh[0] + sh[1] + sh[2] + sh[3];
        atomicAdd(accd, b);
        __threadfence();
        unsigned old = atomicAdd(ticket, 1u);
        if (old == gridDim.x - 1) {
            double total = atomicAdd(accd, 0.0);  // coherent read
            out[0] = (float)(total / (double)NROWS);
        }
    }
}

extern "C" void kernel_launch(void* const* d_in, const int* in_sizes, int n_in,
                              void* d_out, int out_size, void* d_ws, size_t ws_size,
                              hipStream_t stream) {
    const float* in  = (const float*)d_in[0];
    const int*   tgt = (const int*)d_in[1];
    float*       out = (float*)d_out;

    char* ws = (char*)d_ws;
    ushort*   xbs    = (ushort*)(ws + XBS_OFF);
    float*    sqs    = (float*)(ws + SQS_OFF);
    int*      tgts   = (int*)(ws + TGT_OFF);
    unsigned* pmax   = (unsigned*)(ws + PMX_OFF);
    unsigned* nmin   = (unsigned*)(ws + NMN_OFF);
    int*      bincur = (int*)(ws + BIN_OFF);
    double*   accd   = (double*)(ws + ACC_OFF);
    unsigned* ticket = (unsigned*)(ws + TIK_OFF);

    hist_scan_kernel<<<1, 512, 0, stream>>>(tgt, bincur, accd, ticket);
    norm_scatter_kernel<<<NROWS / 4, 256, 0, stream>>>(in, tgt, bincur, xbs, sqs, tgts, pmax, nmin);
    gram_kernel<<<512, 256, 0, stream>>>(xbs, sqs, tgts, pmax, nmin);
    finalize_kernel<<<32, 256, 0, stream>>>(pmax, nmin, sqs, accd, ticket, out);
}

// Round 3
// 155.601 us; speedup vs baseline: 1.0715x; 1.0715x over previous
//
#include <hip/hip_runtime.h>
#include <hip/hip_bf16.h>

#define NROWS  8192
#define DIM    256
#define NCLASS 512
#define MARGIN 0.3f

using bf16x8 = __attribute__((ext_vector_type(8))) short;
using f32x4  = __attribute__((ext_vector_type(4))) float;

__device__ inline ushort f2bf(float f) {
    __hip_bfloat16 h = __float2bfloat16(f);
    return *reinterpret_cast<ushort*>(&h);
}
__device__ inline float bf2f(ushort u) {
    return __uint_as_float(((unsigned)u) << 16);
}
// Order-preserving float<->uint transform: bitwise atomicMax/Min == float max/min.
__device__ inline unsigned f2ord(float f) {
    unsigned b = __float_as_uint(f);
    return (b & 0x80000000u) ? ~b : (b | 0x80000000u);
}
__device__ inline float ord2f(unsigned u) {
    return __uint_as_float((u & 0x80000000u) ? (u & 0x7FFFFFFFu) : ~u);
}
// Async global->LDS, 16B per lane. LDS dest = wave-uniform base + lane*16;
// global src is per-lane.
__device__ inline void ld16_g2l(const void* g, void* l) {
    __builtin_amdgcn_global_load_lds(
        (const __attribute__((address_space(1))) unsigned int*)g,
        (__attribute__((address_space(3))) unsigned int*)l, 16, 0, 0);
}

// ---- workspace layout (bytes) ----
#define XBS_OFF 0u            // 8192*256*2 = 4194304  sorted bf16 rows
#define SQS_OFF 4194304u      // 32768  sorted ||x||^2
#define TGT_OFF 4227072u      // 32768  sorted targets (int)
#define PMX_OFF 4259840u      // 32768  ordered-uint max over positives of (sqc-2acc)
#define NMN_OFF 4292608u      // 32768  ordered-uint min over negatives
#define BIN_OFF 4325376u      // 2048   class bin cursors
#define TIK_OFF 4327424u      // 4      completion ticket

// K1: one block. Histogram of targets -> exclusive scan -> bin cursors.
// Also zeroes the gram completion ticket.
__global__ __launch_bounds__(512) void hist_scan_kernel(
    const int* __restrict__ tgt, int* __restrict__ bincur,
    unsigned* __restrict__ ticket)
{
    __shared__ int h[NCLASS];
    int tid = threadIdx.x;
    h[tid] = 0;
    if (tid == 0) *ticket = 0u;
    __syncthreads();
    for (int k = 0; k < NROWS / NCLASS; ++k)
        atomicAdd(&h[tgt[tid + k * NCLASS]], 1);
    __syncthreads();
    int cnt = h[tid];
    for (int ofs = 1; ofs < NCLASS; ofs <<= 1) {
        int v = (tid >= ofs) ? h[tid - ofs] : 0;
        __syncthreads();
        h[tid] += v;
        __syncthreads();
    }
    bincur[tid] = h[tid] - cnt;
}

// K2: one wave per row. Normalize fp32 -> bf16, scatter to class-sorted slot.
__global__ __launch_bounds__(256) void norm_scatter_kernel(
    const float* __restrict__ in, const int* __restrict__ tgt,
    int* __restrict__ bincur, ushort* __restrict__ xbs,
    float* __restrict__ sqs, int* __restrict__ tgts,
    unsigned* __restrict__ pmax, unsigned* __restrict__ nmin)
{
    int row  = blockIdx.x * 4 + (threadIdx.x >> 6);
    int lane = threadIdx.x & 63;
    float4 v = ((const float4*)(in + (size_t)row * DIM))[lane];
    float ss = v.x * v.x + v.y * v.y + v.z * v.z + v.w * v.w;
#pragma unroll
    for (int m = 1; m < 64; m <<= 1) ss += __shfl_xor(ss, m, 64);
    float inv = 1.0f / (sqrtf(ss) + 1e-12f);

    ushort4 st;
    st.x = f2bf(v.x * inv); st.y = f2bf(v.y * inv);
    st.z = f2bf(v.z * inv); st.w = f2bf(v.w * inv);

    int t = 0, dst = 0;
    if (lane == 0) { t = tgt[row]; dst = atomicAdd(&bincur[t], 1); }
    dst = __shfl(dst, 0); t = __shfl(t, 0);

    ((ushort4*)(xbs + (size_t)dst * DIM))[lane] = st;

    float a0 = bf2f(st.x), a1 = bf2f(st.y), a2 = bf2f(st.z), a3 = bf2f(st.w);
    float s2 = a0 * a0 + a1 * a1 + a2 * a2 + a3 * a3;
#pragma unroll
    for (int m = 1; m < 64; m <<= 1) s2 += __shfl_xor(s2, m, 64);
    if (lane == 0) {
        sqs[dst]  = s2;
        tgts[dst] = t;
        pmax[dst] = 0x007FFFFFu;  // f2ord(-inf)
        nmin[dst] = 0xFF800000u;  // f2ord(+inf)
    }
}

// K3: fused gram + hard-pos/hard-neg + finalize.
// Per-wave-PRIVATE B staging: each wave DMAs its own 16-col stage (8 KB, 8x
// global_load_lds 16B) into a private double buffer and free-runs with counted
// vmcnt(8) waits — ZERO in-loop barriers. Round-0's shared-staging version
// serialized MFMA/LDS/VALU via 16 lockstep __syncthreads (29%+27%+29% = sum);
// round-2's direct-to-VGPR version stalled on L2 latency (prefetch distance
// ~150cyc vs ~300cyc latency). Private DMA staging gives ~400cyc of prefetch
// lead at zero register cost, and 8 free-running waves/CU skew naturally so
// the four pipes (MFMA 16.5us, LDS ~17us, VALU ~12us, L2-DMA ~15us per CU)
// overlap toward max() instead of sum().
// XOR-swizzle pair (LDS-linear dest + pre-swizzled global src on DMA, swizzled
// ds_read_b128) is byte-identical to the round-0-verified layout.
// Last block (ticket) computes the final loss (replaces the old K4 kernel).
__global__ __launch_bounds__(256, 2) void gram_kernel(
    const ushort* __restrict__ xbs, const float* __restrict__ sqs,
    const int* __restrict__ tgts, unsigned* __restrict__ pmax,
    unsigned* __restrict__ nmin, unsigned* __restrict__ ticket,
    float* __restrict__ out)
{
    __shared__ struct {
        char  buf[4][2][8192];  // per-wave private double buffers, 16 cols each
        float sqc[512];         // per-col ||x||^2 for this 512-col chunk
        int   tgc[512];         // per-col class
        int   tga[256];         // per-row class for this block's 256 rows
    } sm;
    __shared__ unsigned lastblk;

    const int wave = threadIdx.x >> 6;
    const int lane = threadIdx.x & 63;
    const int l15  = lane & 15;
    const int quad = lane >> 4;

    // XCD supertile swizzle (bijective, grid 512 = 8 XCD x 64):
    // per XCD: 8x8 blocks -> 2048 rows (1MB) + 4096 cols (2MB) = 3MB < 4MB L2.
    const int id  = blockIdx.x;
    const int xcd = id & 7;
    const int w   = id >> 3;
    const int bx  = (xcd & 3) * 8 + (w & 7);   // 0..31  (256 rows each)
    const int by  = (xcd >> 2) * 8 + (w >> 3); // 0..15  (512 cols each)

    const int mbase = bx * 256 + wave * 64;
    const int nbase = by * 512;

    // Stage per-chunk metadata into LDS (covered by the single barrier below).
    {
        int c = threadIdx.x * 2;
        sm.sqc[c]     = sqs[nbase + c];
        sm.sqc[c + 1] = sqs[nbase + c + 1];
        sm.tgc[c]     = tgts[nbase + c];
        sm.tgc[c + 1] = tgts[nbase + c + 1];
        sm.tga[threadIdx.x] = tgts[bx * 256 + threadIdx.x];
    }

    // Preload A fragments: 4 tiles x full K=256 (long-lived -> AGPR-backed).
    bf16x8 afrag[4][8];
#pragma unroll
    for (int a = 0; a < 4; ++a) {
        const ushort* arow = xbs + (size_t)(mbase + a * 16 + l15) * DIM + quad * 8;
#pragma unroll
        for (int kk = 0; kk < 8; ++kk)
            afrag[a][kk] = *(const bf16x8*)(arow + kk * 32);
    }
    const int rlo = tgts[mbase];       // sorted => wave row-class range
    const int rhi = tgts[mbase + 63];

    // Per-lane global source offsets (xor-swizzle compensation, round-0-verified).
    // DMA instr i writes LDS phys (col=2i+(lane>>5), slot=lane&31); phys slot p
    // of col c holds logical slot p ^ (c&7).
    const int colh = lane >> 5, c31 = lane & 31;
    int offs[4];
#pragma unroll
    for (int j = 0; j < 4; ++j)
        offs[j] = colh * 512 + ((c31 ^ ((2 * j + colh) & 7)) << 4);

    const char* gpanel = (const char*)xbs + (size_t)nbase * 512;
    char* b0 = sm.buf[wave][0];
    char* b1 = sm.buf[wave][1];

    // Issue one 16-col stage (8 KB = 8 DMA instrs) into this wave's buffer.
#define ISSUE(ss_, lb_) do {                                                 \
        const char* g_ = gpanel + (size_t)(ss_) * 8192;                      \
        _Pragma("unroll")                                                    \
        for (int i_ = 0; i_ < 8; ++i_)                                       \
            ld16_g2l(g_ + i_ * 1024 + offs[i_ & 3], (lb_) + i_ * 1024);      \
    } while (0)

    // Prologue: 2 stages in flight per wave (16 outstanding DMA loads).
    ISSUE(0, b0);
    ISSUE(1, b1);
    __syncthreads();   // metadata visible (also drains prologue DMA — once)

    float pm[16], nm[16];
#pragma unroll
    for (int j = 0; j < 16; ++j) { pm[j] = -__builtin_inff(); nm[j] = __builtin_inff(); }

    // One stage: wait for its DMA (counted — next stage stays in flight),
    // swizzled ds_read of the 16-col tile, drain reads (lgkmcnt(0) makes the
    // buffer-overwrite by the re-issued DMA provably safe), re-issue, MFMA,
    // epilogue min/max.
#define STEP(s_, lb_, ISS_, VMSTR_) do {                                     \
        asm volatile("s_waitcnt " VMSTR_ ::: "memory");                      \
        bf16x8 bfrag[8];                                                     \
        _Pragma("unroll")                                                    \
        for (int kk = 0; kk < 8; ++kk)                                       \
            bfrag[kk] = *(const bf16x8*)((lb_) + l15 * 512 +                 \
                                         (((quad + 4 * kk) ^ (l15 & 7)) << 4)); \
        asm volatile("s_waitcnt lgkmcnt(0)" ::: "memory");                   \
        __builtin_amdgcn_sched_barrier(0);                                   \
        if (ISS_) ISSUE((s_) + 2, lb_);                                      \
        f32x4 acc4[4];                                                       \
        __builtin_amdgcn_s_setprio(1);                                       \
        _Pragma("unroll")                                                    \
        for (int a = 0; a < 4; ++a) {                                        \
            f32x4 acc = {0.f, 0.f, 0.f, 0.f};                                \
            _Pragma("unroll")                                                \
            for (int kk = 0; kk < 8; ++kk)                                   \
                acc = __builtin_amdgcn_mfma_f32_16x16x32_bf16(               \
                          afrag[a][kk], bfrag[kk], acc, 0, 0, 0);            \
            acc4[a] = acc;                                                   \
        }                                                                    \
        __builtin_amdgcn_s_setprio(0);                                       \
        const int   t16_ = (s_) * 16;                                        \
        const float sqc_ = sm.sqc[t16_ + l15];                               \
        const int   clo_ = sm.tgc[t16_], chi_ = sm.tgc[t16_ + 15];           \
        if (rlo <= chi_ && clo_ <= rhi) {                                    \
            const int tc_ = sm.tgc[t16_ + l15];                              \
            _Pragma("unroll")                                                \
            for (int a = 0; a < 4; ++a)                                      \
                _Pragma("unroll")                                            \
                for (int i = 0; i < 4; ++i) {                                \
                    const float v_ = fmaf(acc4[a][i], -2.0f, sqc_);          \
                    const bool same_ = (sm.tga[wave * 64 + a * 16 + quad * 4 + i] == tc_); \
                    pm[a * 4 + i] = fmaxf(pm[a * 4 + i], same_ ? v_ : -__builtin_inff()); \
                    nm[a * 4 + i] = fminf(nm[a * 4 + i], same_ ? __builtin_inff() : v_);  \
                }                                                            \
        } else {                                                             \
            _Pragma("unroll")                                                \
            for (int a = 0; a < 4; ++a)                                      \
                _Pragma("unroll")                                            \
                for (int i = 0; i < 4; ++i)                                  \
                    nm[a * 4 + i] = fminf(nm[a * 4 + i], fmaf(acc4[a][i], -2.0f, sqc_)); \
        }                                                                    \
    } while (0)

    // 32 stages of 16 cols. vmcnt(8): stage s done, stage s+1 (8 loads) still
    // in flight. Last two stages have nothing behind them -> vmcnt(8)/vmcnt(0).
#pragma unroll 1
    for (int s = 0; s < 30; s += 2) {
        STEP(s,     b0, 1, "vmcnt(8)");
        STEP(s + 1, b1, 1, "vmcnt(8)");
    }
    STEP(30, b0, 0, "vmcnt(8)");
    STEP(31, b1, 0, "vmcnt(0)");
#undef STEP
#undef ISSUE

    // Reduce across the 16 column-lanes (same quad), then one atomic per row.
#pragma unroll
    for (int m = 1; m < 16; m <<= 1) {
#pragma unroll
        for (int j = 0; j < 16; ++j) {
            pm[j] = fmaxf(pm[j], __shfl_xor(pm[j], m, 64));
            nm[j] = fminf(nm[j], __shfl_xor(nm[j], m, 64));
        }
    }
    if (l15 == 0) {
#pragma unroll
        for (int a = 0; a < 4; ++a)
#pragma unroll
            for (int i = 0; i < 4; ++i) {
                int r = mbase + a * 16 + quad * 4 + i;
                atomicMax(&pmax[r], f2ord(pm[a * 4 + i]));
                atomicMin(&nmin[r], f2ord(nm[a * 4 + i]));
            }
    }

    // ---- fused finalize: last block to finish computes the loss ----
    __threadfence();
    if (threadIdx.x == 0)
        lastblk = (atomicAdd(ticket, 1u) == 511u) ? 1u : 0u;
    __syncthreads();
    if (lastblk) {
        __threadfence();  // acquire: all blocks' pmax/nmin RMWs precede ticket==511
        double s = 0.0;
        for (int r = threadIdx.x; r < NROWS; r += 256) {
            unsigned pu = __hip_atomic_load(&pmax[r], __ATOMIC_RELAXED,
                                            __HIP_MEMORY_SCOPE_AGENT);
            unsigned nu = __hip_atomic_load(&nmin[r], __ATOMIC_RELAXED,
                                            __HIP_MEMORY_SCOPE_AGENT);
            float pe = ord2f(pu);
            float ne = ord2f(nu);
            float ap = sqrtf(fmaxf(sqs[r] + pe, 0.0f));
            float an = (ne > 1e30f) ? (MARGIN + 1.0f) : sqrtf(fmaxf(sqs[r] + ne, 0.0f));
            s += (double)fmaxf(ap - an + MARGIN, 0.0f);
        }
#pragma unroll
        for (int m = 1; m < 64; m <<= 1) s += __shfl_xor(s, m, 64);
        __shared__ double sh[4];
        if ((threadIdx.x & 63) == 0) sh[threadIdx.x >> 6] = s;
        __syncthreads();
        if (threadIdx.x == 0)
            out[0] = (float)((sh[0] + sh[1] + sh[2] + sh[3]) / (double)NROWS);
    }
}

extern "C" void kernel_launch(void* const* d_in, const int* in_sizes, int n_in,
                              void* d_out, int out_size, void* d_ws, size_t ws_size,
                              hipStream_t stream) {
    const float* in  = (const float*)d_in[0];
    const int*   tgt = (const int*)d_in[1];
    float*       out = (float*)d_out;

    char* ws = (char*)d_ws;
    ushort*   xbs    = (ushort*)(ws + XBS_OFF);
    float*    sqs    = (float*)(ws + SQS_OFF);
    int*      tgts   = (int*)(ws + TGT_OFF);
    unsigned* pmax   = (unsigned*)(ws + PMX_OFF);
    unsigned* nmin   = (unsigned*)(ws + NMN_OFF);
    int*      bincur = (int*)(ws + BIN_OFF);
    unsigned* ticket = (unsigned*)(ws + TIK_OFF);

    hist_scan_kernel<<<1, 512, 0, stream>>>(tgt, bincur, ticket);
    norm_scatter_kernel<<<NROWS / 4, 256, 0, stream>>>(in, tgt, bincur, xbs, sqs, tgts, pmax, nmin);
    gram_kernel<<<512, 256, 0, stream>>>(xbs, sqs, tgts, pmax, nmin, ticket, out);
}